// Round 6
// baseline (878.941 us; speedup 1.0000x reference)
//
#include <hip/hip_runtime.h>
#include <hip/hip_bf16.h>
#include <cstdint>

#define SEQ   8192
#define DIN   4096
#define DOUT  4096
#define RANK  16
#define NAD   8
#define KC    (DIN + NAD*RANK)   /* 4224 concatenated K */

using f32x4  = __attribute__((ext_vector_type(4))) float;
using bf16x8 = __attribute__((ext_vector_type(8))) short;   // 8 bf16 in 4 VGPRs

// fp32 -> bf16 round-to-nearest-even (inputs finite)
__device__ __forceinline__ unsigned short f2bf(float f) {
  union { float f; uint32_t u; } v; v.f = f;
  return (unsigned short)((v.u + 0x7fffu + ((v.u >> 16) & 1u)) >> 16);
}

// async global->LDS direct copy, 16B per lane (wave-uniform LDS base + lane*16)
__device__ __forceinline__ void async_copy16(void* lds, const void* gmem) {
  __builtin_amdgcn_global_load_lds(
      (__attribute__((address_space(1))) void*)(uintptr_t)gmem,
      (__attribute__((address_space(3))) void*)(uint32_t)(uintptr_t)lds,
      16, 0, 0);
}

// ---------------- fused conversion kernels ----------------

// blocks [0,4096): x fp32 [SEQ][DIN] -> xcat bf16 rows of stride KC
// blocks [4096,4352): A_buffer fp32 [NAD*RANK][DIN] -> abf bf16 [128][DIN]
__global__ void cvt_xa_kernel(const float* __restrict__ x, unsigned short* __restrict__ xcat,
                              const float* __restrict__ a, unsigned short* __restrict__ abf) {
  if (blockIdx.x < 4096) {
    const int64_t nchunks = (int64_t)SEQ * DIN / 8;
    for (int64_t c = (int64_t)blockIdx.x * 256 + threadIdx.x; c < nchunks;
         c += (int64_t)4096 * 256) {
      int64_t base = c * 8;
      int s = (int)(base >> 12);        // /DIN
      int k = (int)(base & (DIN - 1));
      float4 p = *(const float4*)(x + base);
      float4 q = *(const float4*)(x + base + 4);
      union { unsigned short h[8]; int4 v; } o;
      o.h[0]=f2bf(p.x); o.h[1]=f2bf(p.y); o.h[2]=f2bf(p.z); o.h[3]=f2bf(p.w);
      o.h[4]=f2bf(q.x); o.h[5]=f2bf(q.y); o.h[6]=f2bf(q.z); o.h[7]=f2bf(q.w);
      *(int4*)(xcat + (int64_t)s * KC + k) = o.v;
    }
  } else {
    int c = (blockIdx.x - 4096) * 256 + threadIdx.x;   // 65536 chunks of 8 (256 blocks)
    int64_t base = (int64_t)c * 8;
    float4 p = *(const float4*)(a + base);
    float4 q = *(const float4*)(a + base + 4);
    union { unsigned short h[8]; int4 v; } o;
    o.h[0]=f2bf(p.x); o.h[1]=f2bf(p.y); o.h[2]=f2bf(p.z); o.h[3]=f2bf(p.w);
    o.h[4]=f2bf(q.x); o.h[5]=f2bf(q.y); o.h[6]=f2bf(q.z); o.h[7]=f2bf(q.w);
    *(int4*)(abf + base) = o.v;
  }
}

// blocks [0,4096): weight fp32 [DIN(k)][DOUT(n)] -> wcat bf16 [n][k] stride KC.
//   64x64 tile via LDS transpose: coalesced 256B reads (lanes->n), coalesced
//   128B-granule writes (8B per lane along k). LDS stride 68 ushorts:
//   b32 writes 4-way conflict (1.58x, cheap), b64 reads conflict-free,
//   8B alignment everywhere (136 % 8 == 0).
// blocks [4096,6144): B_buffer fp32 [NAD][DOUT][RANK] -> wcat[n][DIN + e*16 + r]
__global__ void cvt_wb_kernel(const float* __restrict__ w, unsigned short* __restrict__ wcat,
                              const float* __restrict__ Bbuf) {
  if (blockIdx.x < 4096) {
    __shared__ unsigned short tls[64 * 68];   // 8704 B
    int tt = threadIdx.x;
    int n0 = (blockIdx.x & 63) * 64;
    int k0 = (blockIdx.x >> 6) * 64;
#pragma unroll
    for (int j = 0; j < 8; j++) {             // read 2 k-rows per thread-iter
      int idx = j * 256 + tt;                 // 0..2047
      int kk = (idx >> 6) * 2;                // 0,2,..,62
      int nn = idx & 63;
      unsigned int lo = f2bf(w[(int64_t)(k0 + kk)     * DOUT + n0 + nn]);
      unsigned int hi = f2bf(w[(int64_t)(k0 + kk + 1) * DOUT + n0 + nn]);
      *(unsigned int*)&tls[nn * 68 + kk] = lo | (hi << 16);
    }
    __syncthreads();
#pragma unroll
    for (int pp = 0; pp < 4; pp++) {          // write 4 bf16 (8B) per thread-iter
      int flat = pp * 256 + tt;               // 0..1023
      int nn = flat >> 4;                     // 0..63
      int kk4 = (flat & 15) * 4;              // 0,4,..,60
      uint2 v = *(const uint2*)&tls[nn * 68 + kk4];
      *(uint2*)(wcat + (int64_t)(n0 + nn) * KC + k0 + kk4) = v;
    }
  } else {
    int idx = (blockIdx.x - 4096) * 256 + threadIdx.x;  // n*128 + er, 524288 total
    int n = idx >> 7, er = idx & 127;
    int e = er >> 4, r = er & 15;
    float v = Bbuf[((int64_t)e * DOUT + n) * RANK + r];
    wcat[(int64_t)n * KC + DIN + er] = f2bf(v);
  }
}

// ---------------- LoRA-A GEMM v2: fused scale/mask/write, no K-split ----------------
__global__ __launch_bounds__(256) void gemm_lora_a2(
    const unsigned short* __restrict__ A,   // xcat
    const unsigned short* __restrict__ Bb,  // abf [128][DIN]
    const float* __restrict__ scal,
    const int* __restrict__ tok,
    unsigned short* __restrict__ xcat) {
  constexpr int BK = 64;
  __shared__ unsigned short sA[2][16 * BK];    //  4 KB
  __shared__ unsigned short sB[2][128 * BK];   // 32 KB
  int tid = threadIdx.x, wave = tid >> 6, lane = tid & 63;
  int quad = lane >> 4, l16 = lane & 15;
  int row0 = blockIdx.x * 16;
  int f8 = l16 & 7;                            // swizzle key (row&7 == l16&7)

  f32x4 acc[2];
  acc[0] = f32x4{0.f, 0.f, 0.f, 0.f};
  acc[1] = f32x4{0.f, 0.f, 0.f, 0.f};

  auto stage = [&](int b, int kt) {
    int k0 = kt * BK;
    if (tid < 128) {                           // A tile: 16x64 = 128 chunks
      int r = tid >> 3, kc = ((tid & 7) ^ (r & 7)) * 8;
      async_copy16(&sA[b][tid * 8], A + (int64_t)(row0 + r) * KC + k0 + kc);
    }
#pragma unroll
    for (int i = 0; i < 4; i++) {              // B tile: 128x64 = 1024 chunks
      int c = i * 256 + tid;
      int r = c >> 3, kc = ((c & 7) ^ (r & 7)) * 8;
      async_copy16(&sB[b][c * 8], Bb + (int64_t)r * DIN + k0 + kc);
    }
  };

  stage(0, 0);
  __syncthreads();                             // drains vmcnt -> buf0 ready

  for (int kt = 0; kt < DIN / BK; ++kt) {      // 64 iters
    int cur = kt & 1;
    if (kt + 1 < DIN / BK) stage(cur ^ 1, kt + 1);   // in flight during compute
    const unsigned short* sAc = sA[cur];
    const unsigned short* sBc = sB[cur];
#pragma unroll
    for (int ks = 0; ks < 2; ks++) {
      int qp = ((ks * 4 + quad) ^ f8) * 8;     // physical quarter (ushort offset)
      bf16x8 af = *(const bf16x8*)&sAc[l16 * BK + qp];
      bf16x8 b0 = *(const bf16x8*)&sBc[(wave * 32 + l16) * BK + qp];
      bf16x8 b1 = *(const bf16x8*)&sBc[(wave * 32 + 16 + l16) * BK + qp];
      acc[0] = __builtin_amdgcn_mfma_f32_16x16x32_bf16(af, b0, acc[0], 0, 0, 0);
      acc[1] = __builtin_amdgcn_mfma_f32_16x16x32_bf16(af, b1, acc[1], 0, 0, 0);
    }
    __syncthreads();                           // drains next-buf stages; frees cur
  }

  // epilogue: scale, mask by token's adapter, write bf16 LoRA cols of xcat
#pragma unroll
  for (int ni = 0; ni < 2; ni++) {
    int er = wave * 32 + ni * 16 + l16;
    int e = er >> 4;
#pragma unroll
    for (int r = 0; r < 4; r++) {
      int s = row0 + quad * 4 + r;
      float v = acc[ni][r] * scal[s];
      v = (e == tok[s]) ? v : 0.0f;
      xcat[(int64_t)s * KC + DIN + er] = f2bf(v);
    }
  }
}

// ---------------- main GEMM: 256x256 tile, zig-zag, pipelined ds_reads ----------------
// out[s][n] = sum_k xcat[s][k]*wcat[n][k] + bias[n], K=KC=4224 = 66 tiles of BK=64.
// 8 waves (2M x 4N), each owns a 128x64 output tile -> acc[8][4] f32x4.
// LDS: double-buffered A[256][64] + B[256][64] bf16 = 128 KiB (dynamic).
// Quarter swizzle (both-sides): LDS slot (row,q) holds gmem quarter q^(row&7).
// Zig-zag (0,0)->(0,1)->(1,1)->(1,0); B0 and A-halves held in regs across phases.
// NEW (r6): each quadrant's ds_reads hoisted one phase earlier so they overlap
// the previous quadrant's MFMA cluster (bf1 under MFMA(0,0); afB under MFMA(0,1)).
// Separate reg sets afA/afB; compiler inserts counted lgkm waits. Barrier count
// (7/tile) and all stage<->barrier intervals identical to the verified r3 kernel,
// so the staging-safety proof is unchanged (reads only moved earlier within
// their validity window, which starts at tile entry).
// Stage schedule: p0: other-buf B0 <- t+1; p1: A0 <- t+2; p2: B1 <- t+2;
// p3: A1 <- t+2; boundary s_waitcnt vmcnt(6) (6 newest = t+2's groups).

#define CFENCE asm volatile("" ::: "memory")

template<int MQ>
__device__ __forceinline__ void ldsA(const unsigned short* aT, int wm, int l16, int quad,
                                     bf16x8 (&af)[4][2]) {
  int f8 = l16 & 7;
#pragma unroll
  for (int ks = 0; ks < 2; ks++) {
    int qp = ((ks * 4 + quad) ^ f8) * 8;     // physical quarter, ushort offset
#pragma unroll
    for (int mi = 0; mi < 4; mi++)
      af[mi][ks] = *(const bf16x8*)&aT[(wm * 128 + MQ * 64 + mi * 16 + l16) * 64 + qp];
  }
}

template<int NQ>
__device__ __forceinline__ void ldsB(const unsigned short* bT, int wn, int l16, int quad,
                                     bf16x8 (&bq)[2][2]) {
  int f8 = l16 & 7;
#pragma unroll
  for (int ks = 0; ks < 2; ks++) {
    int qp = ((ks * 4 + quad) ^ f8) * 8;
#pragma unroll
    for (int ni = 0; ni < 2; ni++)
      bq[ni][ks] = *(const bf16x8*)&bT[(wn * 64 + NQ * 32 + ni * 16 + l16) * 64 + qp];
  }
}

template<int MQ, int NQ>
__device__ __forceinline__ void mfma_quad(f32x4 (&acc)[8][4], bf16x8 (&af)[4][2],
                                          bf16x8 (&bq)[2][2]) {
  __builtin_amdgcn_s_setprio(1);
#pragma unroll
  for (int mi = 0; mi < 4; mi++)
#pragma unroll
    for (int ni = 0; ni < 2; ni++)
#pragma unroll
      for (int ks = 0; ks < 2; ks++)
        acc[MQ * 4 + mi][NQ * 2 + ni] = __builtin_amdgcn_mfma_f32_16x16x32_bf16(
            af[mi][ks], bq[ni][ks], acc[MQ * 4 + mi][NQ * 2 + ni], 0, 0, 0);
  __builtin_amdgcn_s_setprio(0);
}

// stage A rows {mq*64..+64} u {128+mq*64..+64} of k-tile at col k0 (ushorts)
__device__ __forceinline__ void stage_A(unsigned short* sAb, const unsigned short* Ag,
                                        int mq, int k0, int tid) {
  int rr  = tid >> 3;
  int q8  = (tid & 7) * 8;
  int qc8 = ((tid & 7) ^ (rr & 7)) * 8;
  int r0 = mq * 64 + rr;
  async_copy16(sAb + r0 * 64 + q8, Ag + (int64_t)r0 * KC + k0 + qc8);
  int r1 = r0 + 128;
  async_copy16(sAb + r1 * 64 + q8, Ag + (int64_t)r1 * KC + k0 + qc8);
}

// stage B rows {nq*32 + 64j + 0..31 : j=0..3}
__device__ __forceinline__ void stage_B(unsigned short* sBb, const unsigned short* Bg,
                                        int nq, int k0, int tid) {
  int rB  = ((tid >> 3) & 31) | ((tid >> 8) << 6);
  int q8  = (tid & 7) * 8;
  int qc8 = ((tid & 7) ^ ((tid >> 3) & 7)) * 8;
  int r0 = nq * 32 + rB;
  async_copy16(sBb + r0 * 64 + q8, Bg + (int64_t)r0 * KC + k0 + qc8);
  int r1 = r0 + 128;
  async_copy16(sBb + r1 * 64 + q8, Bg + (int64_t)r1 * KC + k0 + qc8);
}

#define BAR  CFENCE; __builtin_amdgcn_s_barrier(); CFENCE

// One K-tile: 4 zig-zag phases, 7 barriers, stages S0..S3 in the same
// inter-barrier intervals as the verified r3 schedule; ds_reads pipelined.
#define TILE(aT, bT, S0, S1, S2, S3, BND)                         \
  ldsA<0>(aT, wm, l16, quad, afA);                                \
  ldsB<0>(bT, wn, l16, quad, bf0);                                \
  S0; BAR;                                                        \
  ldsB<1>(bT, wn, l16, quad, bf1);                                \
  mfma_quad<0, 0>(acc, afA, bf0);                                 \
  BAR;                                                            \
  S1; BAR;                                                        \
  ldsA<1>(aT, wm, l16, quad, afB);                                \
  mfma_quad<0, 1>(acc, afA, bf1);                                 \
  BAR;                                                            \
  S2; BAR;                                                        \
  mfma_quad<1, 1>(acc, afB, bf1);                                 \
  BAR;                                                            \
  S3;                                                             \
  mfma_quad<1, 0>(acc, afB, bf0);                                 \
  BND;                                                            \
  BAR

__global__ __launch_bounds__(512, 2) void gemm_main8(
    const unsigned short* __restrict__ A,   // xcat [SEQ][KC]
    const unsigned short* __restrict__ B,   // wcat [DOUT][KC]
    const float* __restrict__ bias,
    float* __restrict__ out) {
  extern __shared__ unsigned short smem[];
  unsigned short* a0 = smem;                // A tile even (256x64)
  unsigned short* b0 = smem + 16384;        // B tile even
  unsigned short* a1 = smem + 32768;        // A tile odd
  unsigned short* b1 = smem + 49152;        // B tile odd

  int tid = threadIdx.x, wave = tid >> 6, lane = tid & 63;
  int quad = lane >> 4, l16 = lane & 15;
  int wm = wave >> 2, wn = wave & 3;        // 2M x 4N waves, 128x64 out each

  // XCD-bijective swizzle (512 blocks % 8 == 0)
  int bid = blockIdx.x;
  int cid = (bid & 7) * 64 + (bid >> 3);
  int bm = cid >> 4, bn = cid & 15;
  int row0 = bm * 256, col0 = bn * 256;

  const unsigned short* Ag = A + (int64_t)row0 * KC;
  const unsigned short* Bg = B + (int64_t)col0 * KC;

  const f32x4 zero = {0.f, 0.f, 0.f, 0.f};
  f32x4 acc[8][4];
#pragma unroll
  for (int i = 0; i < 8; i++)
#pragma unroll
    for (int j = 0; j < 4; j++) acc[i][j] = zero;

  bf16x8 afA[4][2], afB[4][2], bf0[2][2], bf1[2][2];

  // prologue: tile0 complete (A0,B0,B1,A1) + tile1 {A0,B1,A1} -> 14 loads
  stage_A(a0, Ag, 0, 0, tid);
  stage_B(b0, Bg, 0, 0, tid);
  stage_B(b0, Bg, 1, 0, tid);
  stage_A(a0, Ag, 1, 0, tid);
  stage_A(a1, Ag, 0, 64, tid);
  stage_B(b1, Bg, 1, 64, tid);
  stage_A(a1, Ag, 1, 64, tid);
  asm volatile("s_waitcnt vmcnt(6)" ::: "memory");  // tile0's 8 landed
  BAR;

#define BND6 asm volatile("s_waitcnt vmcnt(6)" ::: "memory")

  for (int tp = 0; tp < 32; ++tp) {         // tiles 0..63, steady zig-zag
    int kE = tp * 128;
    // even tile 2tp (buf0): t+1 = buf1 @ kE+64, t+2 = buf0 @ kE+128
    TILE(a0, b0,
         stage_B(b1, Bg, 0, kE + 64,  tid),
         stage_A(a0, Ag, 0, kE + 128, tid),
         stage_B(b0, Bg, 1, kE + 128, tid),
         stage_A(a0, Ag, 1, kE + 128, tid),
         BND6);
    // odd tile 2tp+1 (buf1): t+1 = buf0 @ kE+128, t+2 = buf1 @ kE+192
    TILE(a1, b1,
         stage_B(b0, Bg, 0, kE + 128, tid),
         stage_A(a1, Ag, 0, kE + 192, tid),
         stage_B(b1, Bg, 1, kE + 192, tid),
         stage_A(a1, Ag, 1, kE + 192, tid),
         BND6);
  }

  // tile 64 (buf0): only t65's B0 remains to stage; drain fully at boundary
  TILE(a0, b0,
       stage_B(b1, Bg, 0, 4160, tid),
       (void)0, (void)0, (void)0,
       asm volatile("s_waitcnt vmcnt(0)" ::: "memory"));

  // tile 65 (buf1): everything resident, no stages -> no barriers needed
  ldsA<0>(a1, wm, l16, quad, afA);
  ldsB<0>(b1, wn, l16, quad, bf0);
  mfma_quad<0, 0>(acc, afA, bf0);
  ldsB<1>(b1, wn, l16, quad, bf1);
  mfma_quad<0, 1>(acc, afA, bf1);
  ldsA<1>(a1, wm, l16, quad, afB);
  mfma_quad<1, 1>(acc, afB, bf1);
  mfma_quad<1, 0>(acc, afB, bf0);

  // C write + bias
#pragma unroll
  for (int ni = 0; ni < 4; ni++) {
    int col = col0 + wn * 64 + ni * 16 + l16;
    float bv = bias[col];
#pragma unroll
    for (int mi = 0; mi < 8; mi++) {
      int rbase = row0 + wm * 128 + mi * 16 + quad * 4;
#pragma unroll
      for (int r = 0; r < 4; r++)
        out[(int64_t)(rbase + r) * DOUT + col] = acc[mi][ni][r] + bv;
    }
  }
}

// ---------------- slow fp32 fallback (ws too small insurance) ----------------
__global__ void fb_aout(const float* __restrict__ x, const float* __restrict__ Abuf,
                        const float* __restrict__ scal, const int* __restrict__ tok,
                        float* __restrict__ aout) {
  int s = blockIdx.x;
  int e = tok[s];
  __shared__ float red[256];
  for (int r = 0; r < RANK; ++r) {
    float p = 0.f;
    for (int k = threadIdx.x; k < DIN; k += 256)
      p += x[(int64_t)s * DIN + k] * Abuf[((int64_t)e * RANK + r) * DIN + k];
    red[threadIdx.x] = p;
    __syncthreads();
    for (int off = 128; off > 0; off >>= 1) {
      if (threadIdx.x < off) red[threadIdx.x] += red[threadIdx.x + off];
      __syncthreads();
    }
    if (threadIdx.x == 0) aout[s * RANK + r] = red[0] * scal[s];
    __syncthreads();
  }
}
__global__ void fb_out(const float* __restrict__ x, const float* __restrict__ w,
                       const float* __restrict__ bias, const float* __restrict__ Bbuf,
                       const int* __restrict__ tok, const float* __restrict__ aout,
                       float* __restrict__ out) {
  int64_t idx = (int64_t)blockIdx.x * blockDim.x + threadIdx.x;
  int s = (int)(idx >> 12), n = (int)(idx & (DOUT - 1));
  float accv = bias[n];
  for (int k = 0; k < DIN; ++k)
    accv += x[(int64_t)s * DIN + k] * w[(int64_t)k * DOUT + n];
  int e = tok[s];
  float d = 0.f;
  for (int r = 0; r < RANK; ++r)
    d += aout[s * RANK + r] * Bbuf[((int64_t)e * DOUT + n) * RANK + r];
  out[idx] = accv + d;
}

extern "C" void kernel_launch(void* const* d_in, const int* in_sizes, int n_in,
                              void* d_out, int out_size, void* d_ws, size_t ws_size,
                              hipStream_t stream) {
  const float* x    = (const float*)d_in[0];
  const float* w    = (const float*)d_in[1];
  const float* bias = (const float*)d_in[2];
  const float* Abuf = (const float*)d_in[3];
  const float* Bbuf = (const float*)d_in[4];
  const float* scal = (const float*)d_in[5];
  const int*   tok  = (const int*)d_in[6];
  float* out = (float*)d_out;

  const size_t xcat_b = (size_t)SEQ * KC * 2;          // 69,206,016 B
  const size_t wcat_b = (size_t)DOUT * KC * 2;         // 34,603,008 B
  const size_t abf_b  = (size_t)NAD * RANK * DIN * 2;  //  1,048,576 B

  if (ws_size >= xcat_b + wcat_b + abf_b) {
    static bool lds_attr_done = false;
    if (!lds_attr_done) {
      (void)hipFuncSetAttribute((const void*)gemm_main8,
                                hipFuncAttributeMaxDynamicSharedMemorySize, 131072);
      lds_attr_done = true;
    }
    unsigned short* xcat = (unsigned short*)d_ws;
    unsigned short* wcat = (unsigned short*)((char*)d_ws + xcat_b);
    unsigned short* abf  = (unsigned short*)((char*)d_ws + xcat_b + wcat_b);
    cvt_xa_kernel<<<4352, 256, 0, stream>>>(x, xcat, Abuf, abf);
    cvt_wb_kernel<<<6144, 256, 0, stream>>>(w, wcat, Bbuf);
    gemm_lora_a2<<<512, 256, 0, stream>>>(xcat, abf, scal, tok, xcat);
    gemm_main8<<<512, 512, 131072, stream>>>(xcat, wcat, bias, out);
  } else {
    float* aout = (float*)d_ws;  // needs 512 KB
    fb_aout<<<SEQ, 256, 0, stream>>>(x, Abuf, scal, tok, aout);
    fb_out<<<(int)(((int64_t)SEQ * DOUT) / 256), 256, 0, stream>>>(x, w, bias, Bbuf, tok, aout, out);
  }
}

// Round 7
// 552.537 us; speedup vs baseline: 1.5907x; 1.5907x over previous
//
#include <hip/hip_runtime.h>
#include <hip/hip_bf16.h>
#include <cstdint>

#define SEQ   8192
#define DIN   4096
#define DOUT  4096
#define RANK  16
#define NAD   8
#define KC    (DIN + NAD*RANK)   /* 4224 concatenated K */

using f32x4  = __attribute__((ext_vector_type(4))) float;
using bf16x8 = __attribute__((ext_vector_type(8))) short;   // 8 bf16 in 4 VGPRs

// fp32 -> bf16 round-to-nearest-even (inputs finite)
__device__ __forceinline__ unsigned short f2bf(float f) {
  union { float f; uint32_t u; } v; v.f = f;
  return (unsigned short)((v.u + 0x7fffu + ((v.u >> 16) & 1u)) >> 16);
}

// async global->LDS direct copy, 16B per lane (wave-uniform LDS base + lane*16)
__device__ __forceinline__ void async_copy16(void* lds, const void* gmem) {
  __builtin_amdgcn_global_load_lds(
      (__attribute__((address_space(1))) void*)(uintptr_t)gmem,
      (__attribute__((address_space(3))) void*)(uint32_t)(uintptr_t)lds,
      16, 0, 0);
}

// ---------------- fused conversion kernels ----------------

// blocks [0,4096): x fp32 [SEQ][DIN] -> xcat bf16 rows of stride KC
// blocks [4096,4352): A_buffer fp32 [NAD*RANK][DIN] -> abf bf16 [128][DIN]
__global__ void cvt_xa_kernel(const float* __restrict__ x, unsigned short* __restrict__ xcat,
                              const float* __restrict__ a, unsigned short* __restrict__ abf) {
  if (blockIdx.x < 4096) {
    const int64_t nchunks = (int64_t)SEQ * DIN / 8;
    for (int64_t c = (int64_t)blockIdx.x * 256 + threadIdx.x; c < nchunks;
         c += (int64_t)4096 * 256) {
      int64_t base = c * 8;
      int s = (int)(base >> 12);        // /DIN
      int k = (int)(base & (DIN - 1));
      float4 p = *(const float4*)(x + base);
      float4 q = *(const float4*)(x + base + 4);
      union { unsigned short h[8]; int4 v; } o;
      o.h[0]=f2bf(p.x); o.h[1]=f2bf(p.y); o.h[2]=f2bf(p.z); o.h[3]=f2bf(p.w);
      o.h[4]=f2bf(q.x); o.h[5]=f2bf(q.y); o.h[6]=f2bf(q.z); o.h[7]=f2bf(q.w);
      *(int4*)(xcat + (int64_t)s * KC + k) = o.v;
    }
  } else {
    int c = (blockIdx.x - 4096) * 256 + threadIdx.x;   // 65536 chunks of 8 (256 blocks)
    int64_t base = (int64_t)c * 8;
    float4 p = *(const float4*)(a + base);
    float4 q = *(const float4*)(a + base + 4);
    union { unsigned short h[8]; int4 v; } o;
    o.h[0]=f2bf(p.x); o.h[1]=f2bf(p.y); o.h[2]=f2bf(p.z); o.h[3]=f2bf(p.w);
    o.h[4]=f2bf(q.x); o.h[5]=f2bf(q.y); o.h[6]=f2bf(q.z); o.h[7]=f2bf(q.w);
    *(int4*)(abf + base) = o.v;
  }
}

// blocks [0,4096): weight fp32 [DIN(k)][DOUT(n)] -> wcat bf16 [n][k] stride KC.
//   64x64 tile via LDS transpose (coalesced reads, 128B-granule writes).
// blocks [4096,6144): B_buffer fp32 [NAD][DOUT][RANK] -> wcat[n][DIN + e*16 + r]
__global__ void cvt_wb_kernel(const float* __restrict__ w, unsigned short* __restrict__ wcat,
                              const float* __restrict__ Bbuf) {
  if (blockIdx.x < 4096) {
    __shared__ unsigned short tls[64 * 68];   // 8704 B
    int tt = threadIdx.x;
    int n0 = (blockIdx.x & 63) * 64;
    int k0 = (blockIdx.x >> 6) * 64;
#pragma unroll
    for (int j = 0; j < 8; j++) {             // read 2 k-rows per thread-iter
      int idx = j * 256 + tt;                 // 0..2047
      int kk = (idx >> 6) * 2;                // 0,2,..,62
      int nn = idx & 63;
      unsigned int lo = f2bf(w[(int64_t)(k0 + kk)     * DOUT + n0 + nn]);
      unsigned int hi = f2bf(w[(int64_t)(k0 + kk + 1) * DOUT + n0 + nn]);
      *(unsigned int*)&tls[nn * 68 + kk] = lo | (hi << 16);
    }
    __syncthreads();
#pragma unroll
    for (int pp = 0; pp < 4; pp++) {          // write 4 bf16 (8B) per thread-iter
      int flat = pp * 256 + tt;               // 0..1023
      int nn = flat >> 4;                     // 0..63
      int kk4 = (flat & 15) * 4;              // 0,4,..,60
      uint2 v = *(const uint2*)&tls[nn * 68 + kk4];
      *(uint2*)(wcat + (int64_t)(n0 + nn) * KC + k0 + kk4) = v;
    }
  } else {
    int idx = (blockIdx.x - 4096) * 256 + threadIdx.x;  // n*128 + er, 524288 total
    int n = idx >> 7, er = idx & 127;
    int e = er >> 4, r = er & 15;
    float v = Bbuf[((int64_t)e * DOUT + n) * RANK + r];
    wcat[(int64_t)n * KC + DIN + er] = f2bf(v);
  }
}

// ---------------- LoRA-A GEMM v3: 32 rows/block, 8 waves ----------------
// 256 blocks x 512 thr; block = 32 token rows x all 128 er-cols, full K=4096.
// Wave (rm,cn) = (w>>2, w&3): rows rm*16..+16, cols cn*32..+32 -> acc[2] f32x4.
// Halves L2 B-panel traffic vs v2 (32 rows amortize each B stage), doubles
// A-stage issue parallelism. Same verified double-buffer + quarter-swizzle
// + fused scale/mask/f2bf epilogue as v2 (r5, passed/absmax 0.0625).
__global__ __launch_bounds__(512, 2) void gemm_lora_a2(
    const unsigned short* __restrict__ A,   // xcat
    const unsigned short* __restrict__ Bb,  // abf [128][DIN]
    const float* __restrict__ scal,
    const int* __restrict__ tok,
    unsigned short* __restrict__ xcat) {
  constexpr int BK = 64;
  __shared__ unsigned short sA[2][32 * BK];    //  8 KB
  __shared__ unsigned short sB[2][128 * BK];   // 32 KB
  int tid = threadIdx.x, wave = tid >> 6, lane = tid & 63;
  int quad = lane >> 4, l16 = lane & 15;
  int rm = wave >> 2, cn = wave & 3;
  int row0 = blockIdx.x * 32;
  int f8 = l16 & 7;                            // swizzle key (row&7 == l16&7)

  f32x4 acc[2];
  acc[0] = f32x4{0.f, 0.f, 0.f, 0.f};
  acc[1] = f32x4{0.f, 0.f, 0.f, 0.f};

  auto stage = [&](int b, int kt) {
    int k0 = kt * BK;
    if (tid < 256) {                           // A tile: 32x64 = 256 chunks
      int r = tid >> 3, kc = ((tid & 7) ^ (r & 7)) * 8;
      async_copy16(&sA[b][tid * 8], A + (int64_t)(row0 + r) * KC + k0 + kc);
    }
#pragma unroll
    for (int i = 0; i < 2; i++) {              // B tile: 128x64 = 1024 chunks
      int c = i * 512 + tid;
      int r = c >> 3, kc = ((c & 7) ^ (r & 7)) * 8;
      async_copy16(&sB[b][c * 8], Bb + (int64_t)r * DIN + k0 + kc);
    }
  };

  stage(0, 0);
  __syncthreads();                             // drains vmcnt -> buf0 ready

  for (int kt = 0; kt < DIN / BK; ++kt) {      // 64 iters
    int cur = kt & 1;
    if (kt + 1 < DIN / BK) stage(cur ^ 1, kt + 1);   // in flight during compute
    const unsigned short* sAc = sA[cur];
    const unsigned short* sBc = sB[cur];
#pragma unroll
    for (int ks = 0; ks < 2; ks++) {
      int qp = ((ks * 4 + quad) ^ f8) * 8;     // physical quarter (ushort offset)
      bf16x8 af = *(const bf16x8*)&sAc[(rm * 16 + l16) * BK + qp];
      bf16x8 b0 = *(const bf16x8*)&sBc[(cn * 32 + l16) * BK + qp];
      bf16x8 b1 = *(const bf16x8*)&sBc[(cn * 32 + 16 + l16) * BK + qp];
      acc[0] = __builtin_amdgcn_mfma_f32_16x16x32_bf16(af, b0, acc[0], 0, 0, 0);
      acc[1] = __builtin_amdgcn_mfma_f32_16x16x32_bf16(af, b1, acc[1], 0, 0, 0);
    }
    __syncthreads();                           // drains next-buf stages; frees cur
  }

  // epilogue: scale, mask by token's adapter, write bf16 LoRA cols of xcat
#pragma unroll
  for (int ni = 0; ni < 2; ni++) {
    int er = cn * 32 + ni * 16 + l16;
    int e = er >> 4;
#pragma unroll
    for (int r = 0; r < 4; r++) {
      int s = row0 + rm * 16 + quad * 4 + r;
      float v = acc[ni][r] * scal[s];
      v = (e == tok[s]) ? v : 0.0f;
      xcat[(int64_t)s * KC + DIN + er] = f2bf(v);
    }
  }
}

// ---------------- main GEMM: 256x256 tile, zig-zag 8-phase, vmcnt(6) ----------------
// REVERTED to the r3/r5-verified schedule (244 us, MfmaUtil 51.6%).
// r6's ds_read pipelining pushed stage issue ~2 phases later per tile ->
// boundary vmcnt(6) stalls dominated (MfmaUtil 20%, FETCH +84%). Do not re-try
// without keeping stage issue slots fixed.
// out[s][n] = sum_k xcat[s][k]*wcat[n][k] + bias[n], K=KC=4224 = 66 tiles of BK=64.
// 8 waves (2M x 4N), each owns a 128x64 output tile -> acc[8][4] f32x4.
// LDS: double-buffered A[256][64] + B[256][64] bf16 = 128 KiB (dynamic).
// Quarter swizzle (both-sides): LDS slot (row,q) holds gmem quarter q^(row&7).
// Zig-zag quadrant order (0,0)->(0,1)->(1,1)->(1,0), B0 held in regs p0->p3.
// Stage schedule: p0: other-buf B0 <- t+1; p1: A0 <- t+2; p2: B1 <- t+2;
// p3: A1 <- t+2; boundary s_waitcnt vmcnt(6) (6 newest = t+2's groups).

#define CFENCE asm volatile("" ::: "memory")

template<int MQ>
__device__ __forceinline__ void ldsA(const unsigned short* aT, int wm, int l16, int quad,
                                     bf16x8 (&af)[4][2]) {
  int f8 = l16 & 7;
#pragma unroll
  for (int ks = 0; ks < 2; ks++) {
    int qp = ((ks * 4 + quad) ^ f8) * 8;     // physical quarter, ushort offset
#pragma unroll
    for (int mi = 0; mi < 4; mi++)
      af[mi][ks] = *(const bf16x8*)&aT[(wm * 128 + MQ * 64 + mi * 16 + l16) * 64 + qp];
  }
}

template<int NQ>
__device__ __forceinline__ void ldsB(const unsigned short* bT, int wn, int l16, int quad,
                                     bf16x8 (&bq)[2][2]) {
  int f8 = l16 & 7;
#pragma unroll
  for (int ks = 0; ks < 2; ks++) {
    int qp = ((ks * 4 + quad) ^ f8) * 8;
#pragma unroll
    for (int ni = 0; ni < 2; ni++)
      bq[ni][ks] = *(const bf16x8*)&bT[(wn * 64 + NQ * 32 + ni * 16 + l16) * 64 + qp];
  }
}

template<int MQ, int NQ>
__device__ __forceinline__ void mfma_quad(f32x4 (&acc)[8][4], bf16x8 (&af)[4][2],
                                          bf16x8 (&bq)[2][2]) {
  __builtin_amdgcn_s_setprio(1);
#pragma unroll
  for (int mi = 0; mi < 4; mi++)
#pragma unroll
    for (int ni = 0; ni < 2; ni++)
#pragma unroll
      for (int ks = 0; ks < 2; ks++)
        acc[MQ * 4 + mi][NQ * 2 + ni] = __builtin_amdgcn_mfma_f32_16x16x32_bf16(
            af[mi][ks], bq[ni][ks], acc[MQ * 4 + mi][NQ * 2 + ni], 0, 0, 0);
  __builtin_amdgcn_s_setprio(0);
}

// stage A rows {mq*64..+64} u {128+mq*64..+64} of k-tile at col k0 (ushorts)
__device__ __forceinline__ void stage_A(unsigned short* sAb, const unsigned short* Ag,
                                        int mq, int k0, int tid) {
  int rr  = tid >> 3;
  int q8  = (tid & 7) * 8;
  int qc8 = ((tid & 7) ^ (rr & 7)) * 8;
  int r0 = mq * 64 + rr;
  async_copy16(sAb + r0 * 64 + q8, Ag + (int64_t)r0 * KC + k0 + qc8);
  int r1 = r0 + 128;
  async_copy16(sAb + r1 * 64 + q8, Ag + (int64_t)r1 * KC + k0 + qc8);
}

// stage B rows {nq*32 + 64j + 0..31 : j=0..3}
__device__ __forceinline__ void stage_B(unsigned short* sBb, const unsigned short* Bg,
                                        int nq, int k0, int tid) {
  int rB  = ((tid >> 3) & 31) | ((tid >> 8) << 6);
  int q8  = (tid & 7) * 8;
  int qc8 = ((tid & 7) ^ ((tid >> 3) & 7)) * 8;
  int r0 = nq * 32 + rB;
  async_copy16(sBb + r0 * 64 + q8, Bg + (int64_t)r0 * KC + k0 + qc8);
  int r1 = r0 + 128;
  async_copy16(sBb + r1 * 64 + q8, Bg + (int64_t)r1 * KC + k0 + qc8);
}

#define MIDBAR                                                    \
  CFENCE; __builtin_amdgcn_s_barrier();                           \
  asm volatile("s_waitcnt lgkmcnt(0)" ::: "memory")
#define ENDBAR  CFENCE; __builtin_amdgcn_s_barrier(); CFENCE

// One K-tile: 4 zig-zag phases, 7 barriers, stages S0..S3, boundary wait BND.
#define TILE(aT, bT, S0, S1, S2, S3, BND)                         \
  ldsA<0>(aT, wm, l16, quad, af);                                 \
  ldsB<0>(bT, wn, l16, quad, bf0);                                \
  S0; MIDBAR;                                                     \
  mfma_quad<0, 0>(acc, af, bf0);                                  \
  ENDBAR;                                                         \
  ldsB<1>(bT, wn, l16, quad, bf1);                                \
  S1; MIDBAR;                                                     \
  mfma_quad<0, 1>(acc, af, bf1);                                  \
  ENDBAR;                                                         \
  ldsA<1>(aT, wm, l16, quad, af);                                 \
  S2; MIDBAR;                                                     \
  mfma_quad<1, 1>(acc, af, bf1);                                  \
  ENDBAR;                                                         \
  S3; CFENCE;                                                     \
  mfma_quad<1, 0>(acc, af, bf0);                                  \
  BND;                                                            \
  ENDBAR

__global__ __launch_bounds__(512, 2) void gemm_main8(
    const unsigned short* __restrict__ A,   // xcat [SEQ][KC]
    const unsigned short* __restrict__ B,   // wcat [DOUT][KC]
    const float* __restrict__ bias,
    float* __restrict__ out) {
  extern __shared__ unsigned short smem[];
  unsigned short* a0 = smem;                // A tile even (256x64)
  unsigned short* b0 = smem + 16384;        // B tile even
  unsigned short* a1 = smem + 32768;        // A tile odd
  unsigned short* b1 = smem + 49152;        // B tile odd

  int tid = threadIdx.x, wave = tid >> 6, lane = tid & 63;
  int quad = lane >> 4, l16 = lane & 15;
  int wm = wave >> 2, wn = wave & 3;        // 2M x 4N waves, 128x64 out each

  // XCD-bijective swizzle (512 blocks % 8 == 0)
  int bid = blockIdx.x;
  int cid = (bid & 7) * 64 + (bid >> 3);
  int bm = cid >> 4, bn = cid & 15;
  int row0 = bm * 256, col0 = bn * 256;

  const unsigned short* Ag = A + (int64_t)row0 * KC;
  const unsigned short* Bg = B + (int64_t)col0 * KC;

  const f32x4 zero = {0.f, 0.f, 0.f, 0.f};
  f32x4 acc[8][4];
#pragma unroll
  for (int i = 0; i < 8; i++)
#pragma unroll
    for (int j = 0; j < 4; j++) acc[i][j] = zero;

  bf16x8 af[4][2], bf0[2][2], bf1[2][2];

  // prologue: tile0 complete (A0,B0,B1,A1) + tile1 {A0,B1,A1} -> 14 loads
  stage_A(a0, Ag, 0, 0, tid);
  stage_B(b0, Bg, 0, 0, tid);
  stage_B(b0, Bg, 1, 0, tid);
  stage_A(a0, Ag, 1, 0, tid);
  stage_A(a1, Ag, 0, 64, tid);
  stage_B(b1, Bg, 1, 64, tid);
  stage_A(a1, Ag, 1, 64, tid);
  asm volatile("s_waitcnt vmcnt(6)" ::: "memory");  // tile0's 8 landed
  ENDBAR;

#define BND6 asm volatile("s_waitcnt vmcnt(6)" ::: "memory")

  for (int tp = 0; tp < 32; ++tp) {         // tiles 0..63, steady zig-zag
    int kE = tp * 128;
    // even tile 2tp (buf0): t+1 = buf1 @ kE+64, t+2 = buf0 @ kE+128
    TILE(a0, b0,
         stage_B(b1, Bg, 0, kE + 64,  tid),
         stage_A(a0, Ag, 0, kE + 128, tid),
         stage_B(b0, Bg, 1, kE + 128, tid),
         stage_A(a0, Ag, 1, kE + 128, tid),
         BND6);
    // odd tile 2tp+1 (buf1): t+1 = buf0 @ kE+128, t+2 = buf1 @ kE+192
    TILE(a1, b1,
         stage_B(b0, Bg, 0, kE + 128, tid),
         stage_A(a1, Ag, 0, kE + 192, tid),
         stage_B(b1, Bg, 1, kE + 192, tid),
         stage_A(a1, Ag, 1, kE + 192, tid),
         BND6);
  }

  // tile 64 (buf0): only t65's B0 remains to stage; drain fully at boundary
  TILE(a0, b0,
       stage_B(b1, Bg, 0, 4160, tid),
       (void)0, (void)0, (void)0,
       asm volatile("s_waitcnt vmcnt(0)" ::: "memory"));

  // tile 65 (buf1): everything resident, no stages -> no barriers needed
  ldsA<0>(a1, wm, l16, quad, af);
  ldsB<0>(b1, wn, l16, quad, bf0);
  mfma_quad<0, 0>(acc, af, bf0);
  ldsB<1>(b1, wn, l16, quad, bf1);
  mfma_quad<0, 1>(acc, af, bf1);
  ldsA<1>(a1, wm, l16, quad, af);
  mfma_quad<1, 1>(acc, af, bf1);
  mfma_quad<1, 0>(acc, af, bf0);

  // C write + bias
#pragma unroll
  for (int ni = 0; ni < 4; ni++) {
    int col = col0 + wn * 64 + ni * 16 + l16;
    float bv = bias[col];
#pragma unroll
    for (int mi = 0; mi < 8; mi++) {
      int rbase = row0 + wm * 128 + mi * 16 + quad * 4;
#pragma unroll
      for (int r = 0; r < 4; r++)
        out[(int64_t)(rbase + r) * DOUT + col] = acc[mi][ni][r] + bv;
    }
  }
}

// ---------------- slow fp32 fallback (ws too small insurance) ----------------
__global__ void fb_aout(const float* __restrict__ x, const float* __restrict__ Abuf,
                        const float* __restrict__ scal, const int* __restrict__ tok,
                        float* __restrict__ aout) {
  int s = blockIdx.x;
  int e = tok[s];
  __shared__ float red[256];
  for (int r = 0; r < RANK; ++r) {
    float p = 0.f;
    for (int k = threadIdx.x; k < DIN; k += 256)
      p += x[(int64_t)s * DIN + k] * Abuf[((int64_t)e * RANK + r) * DIN + k];
    red[threadIdx.x] = p;
    __syncthreads();
    for (int off = 128; off > 0; off >>= 1) {
      if (threadIdx.x < off) red[threadIdx.x] += red[threadIdx.x + off];
      __syncthreads();
    }
    if (threadIdx.x == 0) aout[s * RANK + r] = red[0] * scal[s];
    __syncthreads();
  }
}
__global__ void fb_out(const float* __restrict__ x, const float* __restrict__ w,
                       const float* __restrict__ bias, const float* __restrict__ Bbuf,
                       const int* __restrict__ tok, const float* __restrict__ aout,
                       float* __restrict__ out) {
  int64_t idx = (int64_t)blockIdx.x * blockDim.x + threadIdx.x;
  int s = (int)(idx >> 12), n = (int)(idx & (DOUT - 1));
  float accv = bias[n];
  for (int k = 0; k < DIN; ++k)
    accv += x[(int64_t)s * DIN + k] * w[(int64_t)k * DOUT + n];
  int e = tok[s];
  float d = 0.f;
  for (int r = 0; r < RANK; ++r)
    d += aout[s * RANK + r] * Bbuf[((int64_t)e * DOUT + n) * RANK + r];
  out[idx] = accv + d;
}

extern "C" void kernel_launch(void* const* d_in, const int* in_sizes, int n_in,
                              void* d_out, int out_size, void* d_ws, size_t ws_size,
                              hipStream_t stream) {
  const float* x    = (const float*)d_in[0];
  const float* w    = (const float*)d_in[1];
  const float* bias = (const float*)d_in[2];
  const float* Abuf = (const float*)d_in[3];
  const float* Bbuf = (const float*)d_in[4];
  const float* scal = (const float*)d_in[5];
  const int*   tok  = (const int*)d_in[6];
  float* out = (float*)d_out;

  const size_t xcat_b = (size_t)SEQ * KC * 2;          // 69,206,016 B
  const size_t wcat_b = (size_t)DOUT * KC * 2;         // 34,603,008 B
  const size_t abf_b  = (size_t)NAD * RANK * DIN * 2;  //  1,048,576 B

  if (ws_size >= xcat_b + wcat_b + abf_b) {
    static bool lds_attr_done = false;
    if (!lds_attr_done) {
      (void)hipFuncSetAttribute((const void*)gemm_main8,
                                hipFuncAttributeMaxDynamicSharedMemorySize, 131072);
      lds_attr_done = true;
    }
    unsigned short* xcat = (unsigned short*)d_ws;
    unsigned short* wcat = (unsigned short*)((char*)d_ws + xcat_b);
    unsigned short* abf  = (unsigned short*)((char*)d_ws + xcat_b + wcat_b);
    cvt_xa_kernel<<<4352, 256, 0, stream>>>(x, xcat, Abuf, abf);
    cvt_wb_kernel<<<6144, 256, 0, stream>>>(w, wcat, Bbuf);
    gemm_lora_a2<<<256, 512, 0, stream>>>(xcat, abf, scal, tok, xcat);
    gemm_main8<<<512, 512, 131072, stream>>>(xcat, wcat, bias, out);
  } else {
    float* aout = (float*)d_ws;  // needs 512 KB
    fb_aout<<<SEQ, 256, 0, stream>>>(x, Abuf, scal, tok, aout);
    fb_out<<<(int)(((int64_t)SEQ * DOUT) / 256), 256, 0, stream>>>(x, w, bias, Bbuf, tok, aout, out);
  }
}

// Round 10
// 521.479 us; speedup vs baseline: 1.6855x; 1.0596x over previous
//
#include <hip/hip_runtime.h>
#include <hip/hip_bf16.h>
#include <cstdint>

#define SEQ   8192
#define DIN   4096
#define DOUT  4096
#define RANK  16
#define NAD   8
#define KC    (DIN + NAD*RANK)   /* 4224 concatenated K */

using f32x4  = __attribute__((ext_vector_type(4))) float;
using bf16x8 = __attribute__((ext_vector_type(8))) short;   // 8 bf16 in 4 VGPRs

// fp32 -> bf16 round-to-nearest-even (inputs finite)
__device__ __forceinline__ unsigned short f2bf(float f) {
  union { float f; uint32_t u; } v; v.f = f;
  return (unsigned short)((v.u + 0x7fffu + ((v.u >> 16) & 1u)) >> 16);
}

// async global->LDS direct copy, 16B per lane (wave-uniform LDS base + lane*16)
__device__ __forceinline__ void async_copy16(void* lds, const void* gmem) {
  __builtin_amdgcn_global_load_lds(
      (__attribute__((address_space(1))) void*)(uintptr_t)gmem,
      (__attribute__((address_space(3))) void*)(uint32_t)(uintptr_t)lds,
      16, 0, 0);
}

// ---------------- kernel A: all weight-side conversions ----------------
// blocks [0,4096): weight fp32 [DIN(k)][DOUT(n)] -> wcat bf16 [n][k] stride KC
//   via 64x64 LDS transpose (coalesced reads, 128B-granule writes).
// blocks [4096,6144): B_buffer fp32 [NAD][DOUT][RANK] -> wcat[n][DIN + e*16 + r]
// blocks [6144,6400): A_buffer fp32 [NAD*RANK][DIN] -> abf bf16 [128][DIN]
__global__ void cvt_wba_kernel(const float* __restrict__ w, unsigned short* __restrict__ wcat,
                               const float* __restrict__ Bbuf,
                               const float* __restrict__ a, unsigned short* __restrict__ abf) {
  if (blockIdx.x < 4096) {
    __shared__ unsigned short tls[64 * 68];   // 8704 B
    int tt = threadIdx.x;
    int n0 = (blockIdx.x & 63) * 64;
    int k0 = (blockIdx.x >> 6) * 64;
#pragma unroll
    for (int j = 0; j < 8; j++) {             // read 2 k-rows per thread-iter
      int idx = j * 256 + tt;                 // 0..2047
      int kk = (idx >> 6) * 2;                // 0,2,..,62
      int nn = idx & 63;
      unsigned int lo = f2bf(w[(int64_t)(k0 + kk)     * DOUT + n0 + nn]);
      unsigned int hi = f2bf(w[(int64_t)(k0 + kk + 1) * DOUT + n0 + nn]);
      *(unsigned int*)&tls[nn * 68 + kk] = lo | (hi << 16);
    }
    __syncthreads();
#pragma unroll
    for (int pp = 0; pp < 4; pp++) {          // write 4 bf16 (8B) per thread-iter
      int flat = pp * 256 + tt;               // 0..1023
      int nn = flat >> 4;                     // 0..63
      int kk4 = (flat & 15) * 4;              // 0,4,..,60
      uint2 v = *(const uint2*)&tls[nn * 68 + kk4];
      *(uint2*)(wcat + (int64_t)(n0 + nn) * KC + k0 + kk4) = v;
    }
  } else if (blockIdx.x < 6144) {
    int idx = (blockIdx.x - 4096) * 256 + threadIdx.x;  // n*128 + er, 524288 total
    int n = idx >> 7, er = idx & 127;
    int e = er >> 4, r = er & 15;
    float v = Bbuf[((int64_t)e * DOUT + n) * RANK + r];
    wcat[(int64_t)n * KC + DIN + er] = f2bf(v);
  } else {
    int c = (blockIdx.x - 6144) * 256 + threadIdx.x;    // 65536 chunks of 8
    int64_t base = (int64_t)c * 8;
    float4 p = *(const float4*)(a + base);
    float4 q = *(const float4*)(a + base + 4);
    union { unsigned short h[8]; int4 v; } o;
    o.h[0]=f2bf(p.x); o.h[1]=f2bf(p.y); o.h[2]=f2bf(p.z); o.h[3]=f2bf(p.w);
    o.h[4]=f2bf(q.x); o.h[5]=f2bf(q.y); o.h[6]=f2bf(q.z); o.h[7]=f2bf(q.w);
    *(int4*)(abf + base) = o.v;
  }
}

// ---------------- kernel B: fused x-convert + LoRA-A GEMM ----------------
// 256 blocks x 512 thr; block = 32 token rows, full K=4096 (64 tiles of BK=64).
// Per tile: load x fp32 (float4/thread, coalesced 256B), convert in-reg,
// write bf16 BOTH to xcat (global, 128B granule) and to quarter-swizzled LDS;
// abf B-panel staged via global_load_lds. MFMA off LDS; double-buffered.
// Eliminates the 67 MB xcat re-read of the old separate LoRA-A kernel.
// Waves (rm,cn)=(w>>2,w&3): rows rm*16..+16, er-cols cn*32..+32 -> acc[2].
// Hazards: sA[next]/sB[next] writes occur after the barrier that retired all
// reads of that buffer; per-iter __syncthreads drains DMA (vmcnt) + ds_writes
// (lgkm). Swizzle invariant (row&7 == l16&7) as in the verified v3.
// Epilogue (scale/mask/f2bf -> xcat LoRA cols) verbatim from verified v3.
__global__ __launch_bounds__(512) void xlora_kernel(
    const float* __restrict__ x,
    const unsigned short* __restrict__ Bb,  // abf [128][DIN]
    const float* __restrict__ scal,
    const int* __restrict__ tok,
    unsigned short* __restrict__ xcat) {
  constexpr int BK = 64;
  __shared__ unsigned short sA[2][32 * BK];    //  8 KB
  __shared__ unsigned short sB[2][128 * BK];   // 32 KB
  int tid = threadIdx.x, wave = tid >> 6, lane = tid & 63;
  int quad = lane >> 4, l16 = lane & 15;
  int rm = wave >> 2, cn = wave & 3;
  int row0 = blockIdx.x * 32;
  int f8 = l16 & 7;                            // swizzle key (row&7 == l16&7)

  // x-load geometry: thread t -> row xr = t>>4, elem col c4 = (t&15)*4
  int xr = tid >> 4, c4 = (tid & 15) * 4;
  int qi = c4 >> 3;                            // quarter index 0..7
  int qsw = ((qi ^ (xr & 7)) * 8) + (c4 & 7);  // swizzled ushort offset in row

  const float* xp = x + (int64_t)(row0 + xr) * DIN + c4;
  unsigned short* xcp = xcat + (int64_t)(row0 + xr) * KC + c4;

  f32x4 acc[2];
  acc[0] = f32x4{0.f, 0.f, 0.f, 0.f};
  acc[1] = f32x4{0.f, 0.f, 0.f, 0.f};

  auto stageB = [&](int b, int kt) {
    int k0 = kt * BK;
#pragma unroll
    for (int i = 0; i < 2; i++) {              // B tile: 128x64 = 1024 chunks
      int c = i * 512 + tid;
      int r = c >> 3, kc = ((c & 7) ^ (r & 7)) * 8;
      async_copy16(&sB[b][c * 8], Bb + (int64_t)r * DIN + k0 + kc);
    }
  };

  // prologue: tile 0 -> regs, convert, LDS + global; stage B0
  {
    float4 xv = *(const float4*)xp;
    stageB(0, 0);
    union { unsigned short h[4]; uint2 v; } o;
    o.h[0]=f2bf(xv.x); o.h[1]=f2bf(xv.y); o.h[2]=f2bf(xv.z); o.h[3]=f2bf(xv.w);
    *(uint2*)&sA[0][xr * BK + qsw] = o.v;
    *(uint2*)xcp = o.v;
  }
  __syncthreads();                             // drains DMA + ds_writes

  for (int kt = 0; kt < DIN / BK; ++kt) {      // 64 iters
    int cur = kt & 1;
    bool hasNext = (kt + 1 < DIN / BK);
    float4 xn;
    if (hasNext) {
      xn = *(const float4*)(xp + (kt + 1) * BK);   // issue early: lands under MFMA
      stageB(cur ^ 1, kt + 1);
    }
    const unsigned short* sAc = sA[cur];
    const unsigned short* sBc = sB[cur];
#pragma unroll
    for (int ks = 0; ks < 2; ks++) {
      int qp = ((ks * 4 + quad) ^ f8) * 8;     // physical quarter (ushort offset)
      bf16x8 af = *(const bf16x8*)&sAc[(rm * 16 + l16) * BK + qp];
      bf16x8 b0 = *(const bf16x8*)&sBc[(cn * 32 + l16) * BK + qp];
      bf16x8 b1 = *(const bf16x8*)&sBc[(cn * 32 + 16 + l16) * BK + qp];
      acc[0] = __builtin_amdgcn_mfma_f32_16x16x32_bf16(af, b0, acc[0], 0, 0, 0);
      acc[1] = __builtin_amdgcn_mfma_f32_16x16x32_bf16(af, b1, acc[1], 0, 0, 0);
    }
    if (hasNext) {                             // convert + write next tile
      union { unsigned short h[4]; uint2 v; } on;
      on.h[0]=f2bf(xn.x); on.h[1]=f2bf(xn.y); on.h[2]=f2bf(xn.z); on.h[3]=f2bf(xn.w);
      *(uint2*)&sA[cur ^ 1][xr * BK + qsw] = on.v;
      *(uint2*)(xcp + (kt + 1) * BK) = on.v;
    }
    __syncthreads();                           // next buffers valid; cur freed
  }

  // epilogue: scale, mask by token's adapter, write bf16 LoRA cols of xcat
#pragma unroll
  for (int ni = 0; ni < 2; ni++) {
    int er = cn * 32 + ni * 16 + l16;
    int e = er >> 4;
#pragma unroll
    for (int r = 0; r < 4; r++) {
      int s = row0 + rm * 16 + quad * 4 + r;
      float v = acc[ni][r] * scal[s];
      v = (e == tok[s]) ? v : 0.0f;
      xcat[(int64_t)s * KC + DIN + er] = f2bf(v);
    }
  }
}

// ---------------- main GEMM: 256x256 tile, zig-zag 8-phase, vmcnt(6) ----------------
// VERIFIED schedule (244 us, MfmaUtil 51.7%) — byte-identical to r7.
// r6's ds_read pipelining pushed stage issue ~2 phases later per tile ->
// boundary vmcnt(6) stalls dominated (MfmaUtil 20%, FETCH +84%). Do not re-try
// without keeping stage issue slots fixed.
// out[s][n] = sum_k xcat[s][k]*wcat[n][k] + bias[n], K=KC=4224 = 66 tiles of BK=64.
// 8 waves (2M x 4N), each owns a 128x64 output tile -> acc[8][4] f32x4.
// LDS: double-buffered A[256][64] + B[256][64] bf16 = 128 KiB (dynamic).
// Quarter swizzle (both-sides): LDS slot (row,q) holds gmem quarter q^(row&7).
// Zig-zag quadrant order (0,0)->(0,1)->(1,1)->(1,0), B0 held in regs p0->p3.
// Stage schedule: p0: other-buf B0 <- t+1; p1: A0 <- t+2; p2: B1 <- t+2;
// p3: A1 <- t+2; boundary s_waitcnt vmcnt(6) (6 newest = t+2's groups).

#define CFENCE asm volatile("" ::: "memory")

template<int MQ>
__device__ __forceinline__ void ldsA(const unsigned short* aT, int wm, int l16, int quad,
                                     bf16x8 (&af)[4][2]) {
  int f8 = l16 & 7;
#pragma unroll
  for (int ks = 0; ks < 2; ks++) {
    int qp = ((ks * 4 + quad) ^ f8) * 8;     // physical quarter, ushort offset
#pragma unroll
    for (int mi = 0; mi < 4; mi++)
      af[mi][ks] = *(const bf16x8*)&aT[(wm * 128 + MQ * 64 + mi * 16 + l16) * 64 + qp];
  }
}

template<int NQ>
__device__ __forceinline__ void ldsB(const unsigned short* bT, int wn, int l16, int quad,
                                     bf16x8 (&bq)[2][2]) {
  int f8 = l16 & 7;
#pragma unroll
  for (int ks = 0; ks < 2; ks++) {
    int qp = ((ks * 4 + quad) ^ f8) * 8;
#pragma unroll
    for (int ni = 0; ni < 2; ni++)
      bq[ni][ks] = *(const bf16x8*)&bT[(wn * 64 + NQ * 32 + ni * 16 + l16) * 64 + qp];
  }
}

template<int MQ, int NQ>
__device__ __forceinline__ void mfma_quad(f32x4 (&acc)[8][4], bf16x8 (&af)[4][2],
                                          bf16x8 (&bq)[2][2]) {
  __builtin_amdgcn_s_setprio(1);
#pragma unroll
  for (int mi = 0; mi < 4; mi++)
#pragma unroll
    for (int ni = 0; ni < 2; ni++)
#pragma unroll
      for (int ks = 0; ks < 2; ks++)
        acc[MQ * 4 + mi][NQ * 2 + ni] = __builtin_amdgcn_mfma_f32_16x16x32_bf16(
            af[mi][ks], bq[ni][ks], acc[MQ * 4 + mi][NQ * 2 + ni], 0, 0, 0);
  __builtin_amdgcn_s_setprio(0);
}

// stage A rows {mq*64..+64} u {128+mq*64..+64} of k-tile at col k0 (ushorts)
__device__ __forceinline__ void stage_A(unsigned short* sAb, const unsigned short* Ag,
                                        int mq, int k0, int tid) {
  int rr  = tid >> 3;
  int q8  = (tid & 7) * 8;
  int qc8 = ((tid & 7) ^ (rr & 7)) * 8;
  int r0 = mq * 64 + rr;
  async_copy16(sAb + r0 * 64 + q8, Ag + (int64_t)r0 * KC + k0 + qc8);
  int r1 = r0 + 128;
  async_copy16(sAb + r1 * 64 + q8, Ag + (int64_t)r1 * KC + k0 + qc8);
}

// stage B rows {nq*32 + 64j + 0..31 : j=0..3}
__device__ __forceinline__ void stage_B(unsigned short* sBb, const unsigned short* Bg,
                                        int nq, int k0, int tid) {
  int rB  = ((tid >> 3) & 31) | ((tid >> 8) << 6);
  int q8  = (tid & 7) * 8;
  int qc8 = ((tid & 7) ^ ((tid >> 3) & 7)) * 8;
  int r0 = nq * 32 + rB;
  async_copy16(sBb + r0 * 64 + q8, Bg + (int64_t)r0 * KC + k0 + qc8);
  int r1 = r0 + 128;
  async_copy16(sBb + r1 * 64 + q8, Bg + (int64_t)r1 * KC + k0 + qc8);
}

#define MIDBAR                                                    \
  CFENCE; __builtin_amdgcn_s_barrier();                           \
  asm volatile("s_waitcnt lgkmcnt(0)" ::: "memory")
#define ENDBAR  CFENCE; __builtin_amdgcn_s_barrier(); CFENCE

// One K-tile: 4 zig-zag phases, 7 barriers, stages S0..S3, boundary wait BND.
#define TILE(aT, bT, S0, S1, S2, S3, BND)                         \
  ldsA<0>(aT, wm, l16, quad, af);                                 \
  ldsB<0>(bT, wn, l16, quad, bf0);                                \
  S0; MIDBAR;                                                     \
  mfma_quad<0, 0>(acc, af, bf0);                                  \
  ENDBAR;                                                         \
  ldsB<1>(bT, wn, l16, quad, bf1);                                \
  S1; MIDBAR;                                                     \
  mfma_quad<0, 1>(acc, af, bf1);                                  \
  ENDBAR;                                                         \
  ldsA<1>(aT, wm, l16, quad, af);                                 \
  S2; MIDBAR;                                                     \
  mfma_quad<1, 1>(acc, af, bf1);                                  \
  ENDBAR;                                                         \
  S3; CFENCE;                                                     \
  mfma_quad<1, 0>(acc, af, bf0);                                  \
  BND;                                                            \
  ENDBAR

__global__ __launch_bounds__(512, 2) void gemm_main8(
    const unsigned short* __restrict__ A,   // xcat [SEQ][KC]
    const unsigned short* __restrict__ B,   // wcat [DOUT][KC]
    const float* __restrict__ bias,
    float* __restrict__ out) {
  extern __shared__ unsigned short smem[];
  unsigned short* a0 = smem;                // A tile even (256x64)
  unsigned short* b0 = smem + 16384;        // B tile even
  unsigned short* a1 = smem + 32768;        // A tile odd
  unsigned short* b1 = smem + 49152;        // B tile odd

  int tid = threadIdx.x, wave = tid >> 6, lane = tid & 63;
  int quad = lane >> 4, l16 = lane & 15;
  int wm = wave >> 2, wn = wave & 3;        // 2M x 4N waves, 128x64 out each

  // XCD-bijective swizzle (512 blocks % 8 == 0)
  int bid = blockIdx.x;
  int cid = (bid & 7) * 64 + (bid >> 3);
  int bm = cid >> 4, bn = cid & 15;
  int row0 = bm * 256, col0 = bn * 256;

  const unsigned short* Ag = A + (int64_t)row0 * KC;
  const unsigned short* Bg = B + (int64_t)col0 * KC;

  const f32x4 zero = {0.f, 0.f, 0.f, 0.f};
  f32x4 acc[8][4];
#pragma unroll
  for (int i = 0; i < 8; i++)
#pragma unroll
    for (int j = 0; j < 4; j++) acc[i][j] = zero;

  bf16x8 af[4][2], bf0[2][2], bf1[2][2];

  // prologue: tile0 complete (A0,B0,B1,A1) + tile1 {A0,B1,A1} -> 14 loads
  stage_A(a0, Ag, 0, 0, tid);
  stage_B(b0, Bg, 0, 0, tid);
  stage_B(b0, Bg, 1, 0, tid);
  stage_A(a0, Ag, 1, 0, tid);
  stage_A(a1, Ag, 0, 64, tid);
  stage_B(b1, Bg, 1, 64, tid);
  stage_A(a1, Ag, 1, 64, tid);
  asm volatile("s_waitcnt vmcnt(6)" ::: "memory");  // tile0's 8 landed
  ENDBAR;

#define BND6 asm volatile("s_waitcnt vmcnt(6)" ::: "memory")

  for (int tp = 0; tp < 32; ++tp) {         // tiles 0..63, steady zig-zag
    int kE = tp * 128;
    // even tile 2tp (buf0): t+1 = buf1 @ kE+64, t+2 = buf0 @ kE+128
    TILE(a0, b0,
         stage_B(b1, Bg, 0, kE + 64,  tid),
         stage_A(a0, Ag, 0, kE + 128, tid),
         stage_B(b0, Bg, 1, kE + 128, tid),
         stage_A(a0, Ag, 1, kE + 128, tid),
         BND6);
    // odd tile 2tp+1 (buf1): t+1 = buf0 @ kE+128, t+2 = buf1 @ kE+192
    TILE(a1, b1,
         stage_B(b0, Bg, 0, kE + 128, tid),
         stage_A(a1, Ag, 0, kE + 192, tid),
         stage_B(b1, Bg, 1, kE + 192, tid),
         stage_A(a1, Ag, 1, kE + 192, tid),
         BND6);
  }

  // tile 64 (buf0): only t65's B0 remains to stage; drain fully at boundary
  TILE(a0, b0,
       stage_B(b1, Bg, 0, 4160, tid),
       (void)0, (void)0, (void)0,
       asm volatile("s_waitcnt vmcnt(0)" ::: "memory"));

  // tile 65 (buf1): everything resident, no stages -> no barriers needed
  ldsA<0>(a1, wm, l16, quad, af);
  ldsB<0>(b1, wn, l16, quad, bf0);
  mfma_quad<0, 0>(acc, af, bf0);
  ldsB<1>(b1, wn, l16, quad, bf1);
  mfma_quad<0, 1>(acc, af, bf1);
  ldsA<1>(a1, wm, l16, quad, af);
  mfma_quad<1, 1>(acc, af, bf1);
  mfma_quad<1, 0>(acc, af, bf0);

  // C write + bias
#pragma unroll
  for (int ni = 0; ni < 4; ni++) {
    int col = col0 + wn * 64 + ni * 16 + l16;
    float bv = bias[col];
#pragma unroll
    for (int mi = 0; mi < 8; mi++) {
      int rbase = row0 + wm * 128 + mi * 16 + quad * 4;
#pragma unroll
      for (int r = 0; r < 4; r++)
        out[(int64_t)(rbase + r) * DOUT + col] = acc[mi][ni][r] + bv;
    }
  }
}

// ---------------- slow fp32 fallback (ws too small insurance) ----------------
__global__ void fb_aout(const float* __restrict__ x, const float* __restrict__ Abuf,
                        const float* __restrict__ scal, const int* __restrict__ tok,
                        float* __restrict__ aout) {
  int s = blockIdx.x;
  int e = tok[s];
  __shared__ float red[256];
  for (int r = 0; r < RANK; ++r) {
    float p = 0.f;
    for (int k = threadIdx.x; k < DIN; k += 256)
      p += x[(int64_t)s * DIN + k] * Abuf[((int64_t)e * RANK + r) * DIN + k];
    red[threadIdx.x] = p;
    __syncthreads();
    for (int off = 128; off > 0; off >>= 1) {
      if (threadIdx.x < off) red[threadIdx.x] += red[threadIdx.x + off];
      __syncthreads();
    }
    if (threadIdx.x == 0) aout[s * RANK + r] = red[0] * scal[s];
    __syncthreads();
  }
}
__global__ void fb_out(const float* __restrict__ x, const float* __restrict__ w,
                       const float* __restrict__ bias, const float* __restrict__ Bbuf,
                       const int* __restrict__ tok, const float* __restrict__ aout,
                       float* __restrict__ out) {
  int64_t idx = (int64_t)blockIdx.x * blockDim.x + threadIdx.x;
  int s = (int)(idx >> 12), n = (int)(idx & (DOUT - 1));
  float accv = bias[n];
  for (int k = 0; k < DIN; ++k)
    accv += x[(int64_t)s * DIN + k] * w[(int64_t)k * DOUT + n];
  int e = tok[s];
  float d = 0.f;
  for (int r = 0; r < RANK; ++r)
    d += aout[s * RANK + r] * Bbuf[((int64_t)e * DOUT + n) * RANK + r];
  out[idx] = accv + d;
}

extern "C" void kernel_launch(void* const* d_in, const int* in_sizes, int n_in,
                              void* d_out, int out_size, void* d_ws, size_t ws_size,
                              hipStream_t stream) {
  const float* x    = (const float*)d_in[0];
  const float* w    = (const float*)d_in[1];
  const float* bias = (const float*)d_in[2];
  const float* Abuf = (const float*)d_in[3];
  const float* Bbuf = (const float*)d_in[4];
  const float* scal = (const float*)d_in[5];
  const int*   tok  = (const int*)d_in[6];
  float* out = (float*)d_out;

  const size_t xcat_b = (size_t)SEQ * KC * 2;          // 69,206,016 B
  const size_t wcat_b = (size_t)DOUT * KC * 2;         // 34,603,008 B
  const size_t abf_b  = (size_t)NAD * RANK * DIN * 2;  //  1,048,576 B

  if (ws_size >= xcat_b + wcat_b + abf_b) {
    static bool lds_attr_done = false;
    if (!lds_attr_done) {
      (void)hipFuncSetAttribute((const void*)gemm_main8,
                                hipFuncAttributeMaxDynamicSharedMemorySize, 131072);
      lds_attr_done = true;
    }
    unsigned short* xcat = (unsigned short*)d_ws;
    unsigned short* wcat = (unsigned short*)((char*)d_ws + xcat_b);
    unsigned short* abf  = (unsigned short*)((char*)d_ws + xcat_b + wcat_b);
    cvt_wba_kernel<<<6400, 256, 0, stream>>>(w, wcat, Bbuf, Abuf, abf);
    xlora_kernel<<<256, 512, 0, stream>>>(x, abf, scal, tok, xcat);
    gemm_main8<<<512, 512, 131072, stream>>>(xcat, wcat, bias, out);
  } else {
    float* aout = (float*)d_ws;  // needs 512 KB
    fb_aout<<<SEQ, 256, 0, stream>>>(x, Abuf, scal, tok, aout);
    fb_out<<<(int)(((int64_t)SEQ * DOUT) / 256), 256, 0, stream>>>(x, w, bias, Bbuf, tok, aout, out);
  }
}